// Round 1
// baseline (46.675 us; speedup 1.0000x reference)
//
#include <hip/hip_runtime.h>

// Depthwise causal conv1d on (B, T, C) fp32.
// y[b,t,c] = sum_{k=0..K-1} w[k,c] * x[b, t+k-(K-1), c], zero-padded left.
// B=4, T=4096, C=2048, K=4.

constexpr int K_TAPS = 4;
constexpr int TCHUNK = 32;   // t-rows per block; halo = K-1 = 3 extra reads
constexpr int BLOCK  = 256;  // threads; each thread owns 4 channels (float4)

__global__ __launch_bounds__(BLOCK) void shortconv_kernel(
    const float* __restrict__ x,   // (B, T, C)
    const float* __restrict__ w,   // (K, 1, C)
    float* __restrict__ y,         // (B, T, C)
    int B, int T, int C)
{
    const int cblocks = C / (4 * BLOCK);          // float4-groups of channels per row
    const int tblocks = T / TCHUNK;

    int bid = blockIdx.x;
    int cb  = bid % cblocks;
    int tb  = (bid / cblocks) % tblocks;
    int b   =  bid / (cblocks * tblocks);

    int c  = (cb * BLOCK + threadIdx.x) * 4;      // starting channel (float4-aligned)
    int t0 = tb * TCHUNK;

    const float* xb = x + (size_t)b * T * C;
    float*       yb = y + (size_t)b * T * C;

    // Per-channel weights: w[k*C + c .. c+3]
    float4 wk[K_TAPS];
#pragma unroll
    for (int k = 0; k < K_TAPS; ++k)
        wk[k] = *reinterpret_cast<const float4*>(w + (size_t)k * C + c);

    // Sliding window: win0 = x[t-3], win1 = x[t-2], win2 = x[t-1]
    float4 zero = make_float4(0.f, 0.f, 0.f, 0.f);
    float4 win0, win1, win2;
    if (t0 >= K_TAPS - 1) {   // block-uniform branch
        win0 = *reinterpret_cast<const float4*>(xb + (size_t)(t0 - 3) * C + c);
        win1 = *reinterpret_cast<const float4*>(xb + (size_t)(t0 - 2) * C + c);
        win2 = *reinterpret_cast<const float4*>(xb + (size_t)(t0 - 1) * C + c);
    } else {                  // t0 == 0: left zero padding
        win0 = zero; win1 = zero; win2 = zero;
    }

#pragma unroll 4
    for (int i = 0; i < TCHUNK; ++i) {
        int t = t0 + i;
        float4 xin = *reinterpret_cast<const float4*>(xb + (size_t)t * C + c);
        float4 out;
        out.x = wk[0].x * win0.x + wk[1].x * win1.x + wk[2].x * win2.x + wk[3].x * xin.x;
        out.y = wk[0].y * win0.y + wk[1].y * win1.y + wk[2].y * win2.y + wk[3].y * xin.y;
        out.z = wk[0].z * win0.z + wk[1].z * win1.z + wk[2].z * win2.z + wk[3].z * xin.z;
        out.w = wk[0].w * win0.w + wk[1].w * win1.w + wk[2].w * win2.w + wk[3].w * xin.w;
        *reinterpret_cast<float4*>(yb + (size_t)t * C + c) = out;
        win0 = win1; win1 = win2; win2 = xin;
    }
}

extern "C" void kernel_launch(void* const* d_in, const int* in_sizes, int n_in,
                              void* d_out, int out_size, void* d_ws, size_t ws_size,
                              hipStream_t stream) {
    const float* x = (const float*)d_in[0];
    const float* w = (const float*)d_in[1];
    float* y = (float*)d_out;

    const int B = 4, T = 4096, C = 2048;
    const int cblocks = C / (4 * BLOCK);   // 2
    const int tblocks = T / TCHUNK;        // 128
    dim3 grid(B * tblocks * cblocks);      // 1024 blocks
    dim3 block(BLOCK);
    shortconv_kernel<<<grid, block, 0, stream>>>(x, w, y, B, T, C);
}